// Round 4
// baseline (229.412 us; speedup 1.0000x reference)
//
#include <hip/hip_runtime.h>
#include <math.h>

// RoPE-2D fused: R(col)*R(row) = R(row+col) (2D rotations compose additively).
// x: [B=32, S=1024, H=16, D=64] fp32. One (b,s) slice = H*D = 1024 floats = 256 float4s.
// Block = 256 threads, 4 slices (16 KB contiguous). Trig is identical across the
// H=16 heads of a slice: only 32 (cos,sin) pairs per slice. Phase 1: 128 threads
// compute 4x32 pairs into LDS (1 div + 1 exp2 + 1 sin + 1 cos each). Phase 2:
// each thread does one ds_read_b128 + 8 FMAs per chunk. Global loads issued
// before phase 1 so HBM latency overlaps the trig compute. Plain loads (m13
// copy recipe), nontemporal stores (pure streaming output).

typedef float vfloat4 __attribute__((ext_vector_type(4)));
typedef float vfloat2 __attribute__((ext_vector_type(2)));

#define CHUNKS 4

__global__ __launch_bounds__(256) void rope2d_kernel(
    const vfloat4* __restrict__ x,
    const int* __restrict__ grid_sizes,
    vfloat4* __restrict__ out)
{
    __shared__ vfloat2 trig[CHUNKS][32];   // [slice][k] = (cos, sin), 1 KB

    const int tid   = threadIdx.x;
    const int base4 = blockIdx.x * (256 * CHUNKS);   // first float4 of this block
    const int bs0   = blockIdx.x * CHUNKS;           // first (b*S+s) slice

    // Issue all global loads up front (overlap HBM latency with trig compute).
    vfloat4 v[CHUNKS];
#pragma unroll
    for (int c = 0; c < CHUNKS; ++c)
        v[c] = x[base4 + c * 256 + tid];

    // Phase 1: waves 0-1 fill the trig table (waves 2-3 skip, no divergence).
    if (tid < 32 * CHUNKS) {
        const int slice = tid >> 5;
        const int k     = tid & 31;
        const int bs    = bs0 + slice;
        const int s     = bs & 1023;              // S = 1024
        const int b     = bs >> 10;
        const int cols  = grid_sizes[2 * b + 1];
        const int i     = s / cols;               // row
        const int j     = s - i * cols;           // col

        const float C       = -0.41524101186092029f;  // -log2(10000)/32
        const float INV_2PI = 0.15915494309189535f;

        const float t = __builtin_amdgcn_exp2f((float)k * C);
        float r = (float)(i + j) * t * INV_2PI;
        r -= floorf(r);                           // revolutions in [0,1)

        vfloat2 cs;
        cs.x = __builtin_amdgcn_cosf(r);
        cs.y = __builtin_amdgcn_sinf(r);
        trig[slice][k] = cs;
    }
    __syncthreads();

    // Phase 2: rotate and store. float4 = pairs (2*kk, 2*kk+1).
    const int kk = tid & 15;
#pragma unroll
    for (int c = 0; c < CHUNKS; ++c) {
        const vfloat2 cs0 = trig[c][2 * kk];      // adjacent -> ds_read_b128
        const vfloat2 cs1 = trig[c][2 * kk + 1];
        vfloat4 o;
        o.x = v[c].x * cs0.x - v[c].y * cs0.y;
        o.y = v[c].y * cs0.x + v[c].x * cs0.y;
        o.z = v[c].z * cs1.x - v[c].w * cs1.y;
        o.w = v[c].w * cs1.x + v[c].z * cs1.y;
        __builtin_nontemporal_store(o, &out[base4 + c * 256 + tid]);
    }
}

extern "C" void kernel_launch(void* const* d_in, const int* in_sizes, int n_in,
                              void* d_out, int out_size, void* d_ws, size_t ws_size,
                              hipStream_t stream) {
    const vfloat4* x  = (const vfloat4*)d_in[0];
    const int*     gs = (const int*)d_in[1];
    vfloat4*       o  = (vfloat4*)d_out;

    const int n4     = in_sizes[0] >> 2;        // 8,388,608 float4s
    const int blocks = n4 / (256 * CHUNKS);     // 8192 blocks, exact coverage

    rope2d_kernel<<<blocks, 256, 0, stream>>>(x, gs, o);
}